// Round 8
// baseline (33.844 us; speedup 1.0000x reference)
//
#include <hip/hip_runtime.h>

struct Cx { float r, i; };

// o = a*h + c : exactly 4 v_fma_f32 (neg folds into VOP3 modifier).
__device__ __forceinline__ Cx cmadd(Cx a, Cx h, Cx c) {
    Cx o;
    o.r = fmaf(a.r, h.r, fmaf(-a.i, h.i, c.r));
    o.i = fmaf(a.r, h.i, fmaf( a.i, h.r, c.i));
    return o;
}

// degree-4/4 Pade rational P(h)/Q(h), Q has implicit +1 constant term.
__device__ __forceinline__ Cx pade(Cx h, const Cx A[5], const Cx Q[4]) {
    Cx num = A[4];
    num = cmadd(num, h, A[3]);
    num = cmadd(num, h, A[2]);
    num = cmadd(num, h, A[1]);
    num = cmadd(num, h, A[0]);
    Cx den = Q[3];
    den = cmadd(den, h, Q[2]);
    den = cmadd(den, h, Q[1]);
    den = cmadd(den, h, Q[0]);
    den = cmadd(den, h, Cx{1.0f, 0.0f});
    float inv = __builtin_amdgcn_rcpf(fmaf(den.r, den.r, den.i * den.i));
    Cx o;
    o.r = fmaf(num.r, den.r,  num.i * den.i) * inv;
    o.i = fmaf(num.i, den.r, -num.r * den.i) * inv;
    return o;
}

__global__ __launch_bounds__(256, 2) void pade_model_kernel(
    const float4* __restrict__ x4,
    const float* __restrict__ W1r, const float* __restrict__ W1i,
    const float* __restrict__ b1r, const float* __restrict__ b1i,
    const float* __restrict__ W2r, const float* __restrict__ W2i,
    const float* __restrict__ b2r, const float* __restrict__ b2i,
    const float* __restrict__ W3r, const float* __restrict__ W3i,
    const float* __restrict__ b3r, const float* __restrict__ b3i,
    const float* __restrict__ a1r, const float* __restrict__ a1i,
    const float* __restrict__ q1r, const float* __restrict__ q1i,
    const float* __restrict__ a2r, const float* __restrict__ a2i,
    const float* __restrict__ q2r, const float* __restrict__ q2i,
    float4* __restrict__ out4, int nthreads)
{
    // ---- stage single-use W/B params into LDS (float2 pairs) ----
    // layout: W1@0..8, B1@8..16, W2@16..48, B2@48..52, W3@52..56, B3@56
    __shared__ float2 lds[57];
    int t = threadIdx.x;
    if (t < 57) {
        float r, i;
        if      (t <  8) { r = W1r[t];      i = W1i[t]; }
        else if (t < 16) { r = b1r[t - 8];  i = b1i[t - 8]; }
        else if (t < 48) { r = W2r[t - 16]; i = W2i[t - 16]; }
        else if (t < 52) { r = b2r[t - 48]; i = b2i[t - 48]; }
        else if (t < 56) { r = W3r[t - 52]; i = W3i[t - 52]; }
        else             { r = b3r[0];      i = b3i[0]; }
        lds[t] = {r, i};
    }
    __syncthreads();

    // ---- multi-use Pade coefficients: SGPR-resident ----
    Cx A1[5], Q1[4], A2[5], Q2[4];
    #pragma unroll
    for (int j = 0; j < 5; ++j) { A1[j] = {a1r[j], a1i[j]}; A2[j] = {a2r[j], a2i[j]}; }
    #pragma unroll
    for (int j = 0; j < 4; ++j) { Q1[j] = {q1r[j], q1i[j]}; Q2[j] = {q2r[j], q2i[j]}; }

    auto L = [&](int k) -> Cx { float2 v = lds[k]; return {v.x, v.y}; };

    // one full forward pass (all coefficient reads from LDS/SGPR)
    auto fwd = [&](float xr, float xi) -> Cx {
        float er = __expf(xr);
        Cx z{er * __cosf(xi), er * __sinf(xi)};
        Cx h2[4];
        #pragma unroll
        for (int k = 0; k < 4; ++k) h2[k] = L(48 + k);
        #pragma unroll
        for (int j = 0; j < 8; ++j) {
            Cx u = pade(cmadd(z, L(j), L(8 + j)), A1, Q1);
            #pragma unroll
            for (int k = 0; k < 4; ++k)
                h2[k] = cmadd(u, L(16 + j * 4 + k), h2[k]);
        }
        #pragma unroll
        for (int k = 0; k < 4; ++k) h2[k] = pade(h2[k], A2, Q2);
        Cx o = L(56);
        #pragma unroll
        for (int k = 0; k < 4; ++k) o = cmadd(h2[k], L(52 + k), o);
        return o;
    };

    // ---- 4 samples/thread: two coalesced float4 chunks, stride-split ----
    int i0 = blockIdx.x * blockDim.x + t;
    int i1 = i0 + nthreads;
    float4 v0 = x4[i0];
    float4 v1 = x4[i1];

    Cx o0 = fwd(v0.x, v0.y);
    Cx o1 = fwd(v0.z, v0.w);
    Cx o2 = fwd(v1.x, v1.y);
    Cx o3 = fwd(v1.z, v1.w);

    out4[i0] = {o0.r, o0.i, o1.r, o1.i};
    out4[i1] = {o2.r, o2.i, o3.r, o3.i};
}

extern "C" void kernel_launch(void* const* d_in, const int* in_sizes, int n_in,
                              void* d_out, int out_size, void* d_ws, size_t ws_size,
                              hipStream_t stream) {
    // setup_inputs() dict order:
    // 0:x 1:W1r 2:W1i 3:b1r 4:b1i 5:W2r 6:W2i 7:b2r 8:b2i
    // 9:W3r 10:W3i 11:b3r 12:b3i 13:a1r 14:a1i 15:q1r 16:q1i
    // 17:a2r 18:a2i 19:q2r 20:q2i
    const float4* x4 = (const float4*)d_in[0];
    const float* W1r = (const float*)d_in[1];
    const float* W1i = (const float*)d_in[2];
    const float* b1r = (const float*)d_in[3];
    const float* b1i = (const float*)d_in[4];
    const float* W2r = (const float*)d_in[5];
    const float* W2i = (const float*)d_in[6];
    const float* b2r = (const float*)d_in[7];
    const float* b2i = (const float*)d_in[8];
    const float* W3r = (const float*)d_in[9];
    const float* W3i = (const float*)d_in[10];
    const float* b3r = (const float*)d_in[11];
    const float* b3i = (const float*)d_in[12];
    const float* a1r = (const float*)d_in[13];
    const float* a1i = (const float*)d_in[14];
    const float* q1r = (const float*)d_in[15];
    const float* q1i = (const float*)d_in[16];
    const float* a2r = (const float*)d_in[17];
    const float* a2i = (const float*)d_in[18];
    const float* q2r = (const float*)d_in[19];
    const float* q2i = (const float*)d_in[20];

    int n = in_sizes[0] / 2;       // samples (B = 2^21)
    int nthreads = n / 4;          // 4 samples per thread = 524288 threads
    float4* out4 = (float4*)d_out;

    dim3 block(256);
    dim3 grid(nthreads / 256);     // exact: 2048 blocks
    pade_model_kernel<<<grid, block, 0, stream>>>(
        x4, W1r, W1i, b1r, b1i, W2r, W2i, b2r, b2i, W3r, W3i, b3r, b3i,
        a1r, a1i, q1r, q1i, a2r, a2i, q2r, q2i, out4, nthreads);
}